// Round 12
// baseline (329.067 us; speedup 1.0000x reference)
//
#include <hip/hip_runtime.h>
#include <hip/hip_bf16.h>

#define DIM 128
#define NLAYER 4
#define CHUNK 4096     // edges per block in CSR-build pass 1

typedef _Float16 f16x8 __attribute__((ext_vector_type(8)));
typedef _Float16 f16x2 __attribute__((ext_vector_type(2)));
typedef float f32x4 __attribute__((ext_vector_type(4)));

// Physical slot map for the 10 logical hop slots (ring allocation, peak live = 6).
static constexpr int PHYS[10] = {0, 4, 1, 0, 5, 2, 1, 4, 6, 3};

// ============ CSR build: bucketed two-pass, coalesced final writes ============

__global__ __launch_bounds__(256) void k_hist1(const int* __restrict__ dst, int E,
                                               int B1, int NBKT, int* __restrict__ ghist) {
    __shared__ int h[256];
    h[threadIdx.x] = 0;
    __syncthreads();
    const int base = blockIdx.x * CHUNK;
    #pragma unroll
    for (int i = 0; i < CHUNK / 256; ++i) {
        int e = base + i * 256 + threadIdx.x;
        if (e < E) atomicAdd(&h[dst[e] >> 8], 1);
    }
    __syncthreads();
    if (threadIdx.x < NBKT) ghist[threadIdx.x * B1 + blockIdx.x] = h[threadIdx.x];
}

// single-block exclusive scan of n (<= 32768) elems: two-pass per thread, no scratch
__global__ __launch_bounds__(1024) void k_scan_all(const int* __restrict__ in, int n,
                                                   int* __restrict__ outEx) {
    __shared__ int sd[1024];
    const int tid = threadIdx.x;
    const int ipt = (n + 1023) >> 10;
    const int base = tid * ipt;
    int s = 0;
    for (int j = 0; j < ipt; ++j) {
        int i = base + j;
        s += (i < n) ? in[i] : 0;
    }
    sd[tid] = s;
    __syncthreads();
    for (int o = 1; o < 1024; o <<= 1) {
        int t = (tid >= o) ? sd[tid - o] : 0;
        __syncthreads();
        sd[tid] += t;
        __syncthreads();
    }
    int run = (tid > 0) ? sd[tid - 1] : 0;
    for (int j = 0; j < ipt; ++j) {
        int i = base + j;
        if (i < n) {
            outEx[i] = run;
            run += in[i];
        }
    }
    if (tid == 1023) outEx[n] = sd[1023];
}

__global__ __launch_bounds__(256) void k_scat1(const int* __restrict__ srcA,
                                               const int* __restrict__ dstA,
                                               const int* __restrict__ typA,
                                               const int* __restrict__ hopA,
                                               int E, int B1, int NBKT,
                                               const int* __restrict__ gcur,
                                               unsigned long long* __restrict__ ebuf) {
    __shared__ int cur[256];
    if (threadIdx.x < NBKT) cur[threadIdx.x] = gcur[threadIdx.x * B1 + blockIdx.x];
    __syncthreads();
    const int base = blockIdx.x * CHUNK;
    #pragma unroll
    for (int i = 0; i < CHUNK / 256; ++i) {
        int e = base + i * 256 + threadIdx.x;
        if (e < E) {
            int d = dstA[e];
            unsigned w = ((unsigned)srcA[e] << 8) | ((unsigned)typA[e] << 24)
                       | ((unsigned)hopA[e] << 26);
            int p = atomicAdd(&cur[d >> 8], 1);
            ebuf[p] = ((unsigned long long)(unsigned)d << 32) | w;
        }
    }
}

__global__ __launch_bounds__(256) void k_finalize(const unsigned long long* __restrict__ ebuf,
                                                  const int* __restrict__ gcur,
                                                  int E, int B1, int NBKT, int N,
                                                  unsigned* __restrict__ csr,
                                                  int* __restrict__ row_ptr) {
    __shared__ int cnt[256], sd[256], off2[256];
    __shared__ unsigned stg[8192];
    const int bkt = blockIdx.x, tid = threadIdx.x;
    const int base = gcur[bkt * B1];
    const int endv = (bkt + 1 < NBKT) ? gcur[(bkt + 1) * B1] : E;
    const int n = endv - base;

    cnt[tid] = 0;
    __syncthreads();
    for (int i = tid; i < n; i += 256)
        atomicAdd(&cnt[(int)((ebuf[base + i] >> 32) & 255)], 1);
    __syncthreads();

    sd[tid] = cnt[tid];
    __syncthreads();
    for (int o = 1; o < 256; o <<= 1) {
        int t = (tid >= o) ? sd[tid - o] : 0;
        __syncthreads();
        sd[tid] += t;
        __syncthreads();
    }
    const int ex = (tid > 0) ? sd[tid - 1] : 0;
    off2[tid] = ex;
    const int node = bkt * 256 + tid;
    if (node < N) row_ptr[node] = base + ex;
    if (bkt == NBKT - 1 && tid == 0) row_ptr[N] = E;
    __syncthreads();

    for (int i = tid; i < n; i += 256) {
        const unsigned long long ld = ebuf[base + i];
        const int r = atomicAdd(&off2[(int)((ld >> 32) & 255)], 1);
        stg[r] = (unsigned)ld;
    }
    __syncthreads();
    for (int i = tid; i < n; i += 256) csr[base + i] = stg[i];
}

// ---------------- merged conversions + bias: blockIdx-sectioned ----------------
// blocks [0, NXB): convX ; [NXB, NXB+13): convW ; [NXB+13, NXB+17): bias

__global__ __launch_bounds__(256) void k_misc(const float* __restrict__ x,
                                              _Float16* __restrict__ xh0, int NXB, int nElem,
                                              const float* __restrict__ W_edge,
                                              const float* __restrict__ W_hop,
                                              _Float16* __restrict__ Wt,
                                              const float* __restrict__ b_edge,
                                              const float* __restrict__ b_hop,
                                              float* __restrict__ bias_sums) {
    const int b = blockIdx.x, tid = threadIdx.x;
    if (b < NXB) {
        int i = (b * 256 + tid) * 8;
        if (i >= nElem) return;
        float4 a0 = ((const float4*)(x + i))[0];
        float4 a1 = ((const float4*)(x + i))[1];
        f16x8 o;
        o[0] = (_Float16)a0.x; o[1] = (_Float16)a0.y; o[2] = (_Float16)a0.z; o[3] = (_Float16)a0.w;
        o[4] = (_Float16)a1.x; o[5] = (_Float16)a1.y; o[6] = (_Float16)a1.z; o[7] = (_Float16)a1.w;
        *(f16x8*)(xh0 + i) = o;
    } else if (b < NXB + 13) {
        int s = b - NXB;
        const float* src = (s < 3) ? (W_edge + (size_t)s * DIM * DIM)
                                   : (W_hop + (size_t)(s - 3) * DIM * DIM);
        _Float16* dstp = Wt + (size_t)s * DIM * DIM;
        for (int it = 0; it < 64; ++it) {
            int e = it * 256 + tid;
            int n = e >> 7, k = e & 127;
            dstp[e] = (_Float16)src[k * DIM + n];
        }
    } else {
        if (tid >= DIM) return;
        int t = b - NXB - 13;
        float s = b_edge[tid] + b_edge[DIM + tid] + b_edge[2 * DIM + tid];
        int base = t * (t + 1) / 2;
        for (int k = 1; k <= t + 1; ++k) s += b_hop[(base + k - 1) * DIM + tid];
        bias_sums[t * DIM + tid] = s;
    }
}

// -------- phase 1: single-pass gather; future hop slots accumulated now --------
// 256-thr blocks, 1 node/wave; node pinned to SGPR via readfirstlane so the csr
// words scalarize (s_load + uniform branches) while 4 waves share one WG slot.

struct GatherArgs {
    const _Float16* __restrict__ xt;    // xh[TAU]
    _Float16* __restrict__ Atype;       // [3][N][128]
    _Float16* __restrict__ Ahop;        // [7][N][128] physical ring slots
    const int* __restrict__ row_ptr;
    const unsigned* __restrict__ csr;
    int N;
};

template <int TAU>
__global__ __launch_bounds__(256) void k_gather(GatherArgs a) {
    const int lane = threadIdx.x & 63;
    const int node = __builtin_amdgcn_readfirstlane(blockIdx.x * 4 + (threadIdx.x >> 6));
    if (node >= a.N) return;
    const size_t NS = (size_t)a.N * DIM;

    const char* xtl = (const char*)a.xt + lane * 4;

    float t0x = 0, t0y = 0, t1x = 0, t1y = 0, t2x = 0, t2y = 0;
    float h1x = 0, h1y = 0, h2x = 0, h2y = 0, h3x = 0, h3y = 0, h4x = 0, h4y = 0;

    const int e0 = a.row_ptr[node], e1 = a.row_ptr[node + 1];
    int e = e0;

    #define ACCUM(m, v)                                                        \
        {                                                                      \
            const int typ = (int)((m) >> 24) & 3;                              \
            const int hop = (int)((m) >> 26);                                  \
            const float vx = (float)(v)[0], vy = (float)(v)[1];                \
            if (typ == 0)      { t0x += vx; t0y += vy; }                       \
            else if (typ == 1) { t1x += vx; t1y += vy; }                       \
            else               { t2x += vx; t2y += vy; }                       \
            if (hop == 1)                    { h1x += vx; h1y += vy; }         \
            else if (TAU <= 2 && hop == 2)   { h2x += vx; h2y += vy; }         \
            else if (TAU <= 1 && hop == 3)   { h3x += vx; h3y += vy; }         \
            else if (TAU == 0 && hop == 4)   { h4x += vx; h4y += vy; }         \
        }

    for (; e + 8 <= e1; e += 8) {
        unsigned mm[8];
        #pragma unroll
        for (int j = 0; j < 8; ++j) mm[j] = a.csr[e + j];
        f16x2 vv[8];
        #pragma unroll
        for (int j = 0; j < 8; ++j)
            vv[j] = *(const f16x2*)(xtl + (mm[j] & 0xFFFFFF));
        #pragma unroll
        for (int j = 0; j < 8; ++j) ACCUM(mm[j], vv[j])
    }
    for (; e + 4 <= e1; e += 4) {
        unsigned mm[4];
        #pragma unroll
        for (int j = 0; j < 4; ++j) mm[j] = a.csr[e + j];
        f16x2 vv[4];
        #pragma unroll
        for (int j = 0; j < 4; ++j)
            vv[j] = *(const f16x2*)(xtl + (mm[j] & 0xFFFFFF));
        #pragma unroll
        for (int j = 0; j < 4; ++j) ACCUM(mm[j], vv[j])
    }
    for (; e < e1; ++e) {
        const unsigned m = a.csr[e];
        const f16x2 v = *(const f16x2*)(xtl + (m & 0xFFFFFF));
        ACCUM(m, v)
    }
    #undef ACCUM

    _Float16* tb = a.Atype + (size_t)node * DIM;
    f16x2 o;
    o[0] = (_Float16)t0x; o[1] = (_Float16)t0y; ((f16x2*)(tb + 0 * NS))[lane] = o;
    o[0] = (_Float16)t1x; o[1] = (_Float16)t1y; ((f16x2*)(tb + 1 * NS))[lane] = o;
    o[0] = (_Float16)t2x; o[1] = (_Float16)t2y; ((f16x2*)(tb + 2 * NS))[lane] = o;

    _Float16* hb = a.Ahop + (size_t)node * DIM;
    {
        constexpr int P1 = PHYS[(TAU * (TAU + 1)) / 2];
        o[0] = (_Float16)h1x; o[1] = (_Float16)h1y; ((f16x2*)(hb + (size_t)P1 * NS))[lane] = o;
    }
    if constexpr (TAU <= 2) {
        constexpr int P2 = PHYS[((TAU + 1) * (TAU + 2)) / 2 + 1];
        o[0] = (_Float16)h2x; o[1] = (_Float16)h2y; ((f16x2*)(hb + (size_t)P2 * NS))[lane] = o;
    }
    if constexpr (TAU <= 1) {
        constexpr int P3 = PHYS[((TAU + 2) * (TAU + 3)) / 2 + 2];
        o[0] = (_Float16)h3x; o[1] = (_Float16)h3y; ((f16x2*)(hb + (size_t)P3 * NS))[lane] = o;
    }
    if constexpr (TAU == 0) {
        constexpr int P4 = PHYS[9];
        o[0] = (_Float16)h4x; o[1] = (_Float16)h4y; ((f16x2*)(hb + (size_t)P4 * NS))[lane] = o;
    }
}

// -------- phase 2: C = sum_s A_s @ W_s, fused bias+relu+residual+L2norm --------

struct GemmArgs {
    const _Float16* Aslot[7];
    const _Float16* Wt;
    const _Float16* xin;
    const float* bias;
    float* outf;
    _Float16* outh;
    int N;
    int wsel[7];
};

template <int NSUB>
__global__ __launch_bounds__(128, 2) void k_gemm(GemmArgs a) {
    __shared__ __align__(16) _Float16 Wlds[DIM * DIM];   // 32 KB, swizzled
    const int tid = threadIdx.x, wv = tid >> 6, lane = tid & 63;
    const int rowBase = blockIdx.x * 64 + wv * 32;
    const int lr = lane & 15, lg = lane >> 4;

    int r0 = rowBase + lr, r1 = rowBase + 16 + lr;
    if (r0 >= a.N) r0 = a.N - 1;
    if (r1 >= a.N) r1 = a.N - 1;

    f32x4 acc[2][8];
    #pragma unroll
    for (int rt = 0; rt < 2; ++rt)
        #pragma unroll
        for (int ct = 0; ct < 8; ++ct)
            acc[rt][ct] = (f32x4){0.f, 0.f, 0.f, 0.f};

    const int sw = (lr & 7) << 4;

    {
        const _Float16* Ws = a.Wt + (size_t)a.wsel[0] * (DIM * DIM);
        f16x8 w[16];
        #pragma unroll
        for (int i = 0; i < 16; ++i)
            w[i] = *(const f16x8*)((const char*)Ws + i * 2048 + tid * 16);
        #pragma unroll
        for (int i = 0; i < 16; ++i) {
            const int p = i * 2048 + tid * 16;
            const int q = p ^ (((p >> 8) & 7) << 4);
            *(f16x8*)((char*)Wlds + q) = w[i];
        }
    }
    f16x8 afA[2][4], afB[2][4];
    #pragma unroll
    for (int ks = 0; ks < 4; ++ks) {
        afA[0][ks] = *(const f16x8*)(a.Aslot[0] + (size_t)r0 * DIM + ks * 32 + lg * 8);
        afB[0][ks] = *(const f16x8*)(a.Aslot[0] + (size_t)r1 * DIM + ks * 32 + lg * 8);
    }
    __syncthreads();

    #pragma unroll
    for (int s = 0; s < NSUB; ++s) {
        const int cur = s & 1, nxt = cur ^ 1;
        f16x8 w[16];
        if (s + 1 < NSUB) {
            const _Float16* Wn = a.Wt + (size_t)a.wsel[s + 1] * (DIM * DIM);
            #pragma unroll
            for (int i = 0; i < 16; ++i)
                w[i] = *(const f16x8*)((const char*)Wn + i * 2048 + tid * 16);
            const _Float16* An = a.Aslot[s + 1];
            #pragma unroll
            for (int ks = 0; ks < 4; ++ks) {
                afA[nxt][ks] = *(const f16x8*)(An + (size_t)r0 * DIM + ks * 32 + lg * 8);
                afB[nxt][ks] = *(const f16x8*)(An + (size_t)r1 * DIM + ks * 32 + lg * 8);
            }
        }
        #pragma unroll
        for (int ks = 0; ks < 4; ++ks) {
            const int cb = (ks * 32 + lg * 8) * 2;
            #pragma unroll
            for (int ct = 0; ct < 8; ++ct) {
                const int addr = (ct * 16 + lr) * 256 + (cb ^ sw);
                const f16x8 bf = *(const f16x8*)((const char*)Wlds + addr);
                acc[0][ct] = __builtin_amdgcn_mfma_f32_16x16x32_f16(afA[cur][ks], bf, acc[0][ct], 0, 0, 0);
                acc[1][ct] = __builtin_amdgcn_mfma_f32_16x16x32_f16(afB[cur][ks], bf, acc[1][ct], 0, 0, 0);
            }
        }
        __syncthreads();
        if (s + 1 < NSUB) {
            #pragma unroll
            for (int i = 0; i < 16; ++i) {
                const int p = i * 2048 + tid * 16;
                const int q = p ^ (((p >> 8) & 7) << 4);
                *(f16x8*)((char*)Wlds + q) = w[i];
            }
            __syncthreads();
        }
    }

    float bv[8];
    #pragma unroll
    for (int ct = 0; ct < 8; ++ct) bv[ct] = a.bias[ct * 16 + lr];

    #pragma unroll
    for (int rt = 0; rt < 2; ++rt) {
        #pragma unroll
        for (int rg = 0; rg < 4; ++rg) {
            const int row = rowBase + rt * 16 + lg * 4 + rg;
            const int rr = (row < a.N) ? row : a.N - 1;
            float v[8];
            float ss = 0.f;
            #pragma unroll
            for (int ct = 0; ct < 8; ++ct) {
                const float xval = (float)a.xin[(size_t)rr * DIM + ct * 16 + lr];
                const float tv = fmaxf(acc[rt][ct][rg] + bv[ct], 0.f) + xval;
                v[ct] = tv;
                ss += tv * tv;
            }
            ss += __shfl_xor(ss, 1, 64);
            ss += __shfl_xor(ss, 2, 64);
            ss += __shfl_xor(ss, 4, 64);
            ss += __shfl_xor(ss, 8, 64);
            const float inv = 1.f / fmaxf(sqrtf(ss), 1e-12f);
            if (row < a.N) {
                #pragma unroll
                for (int ct = 0; ct < 8; ++ct) {
                    const int col = ct * 16 + lr;
                    const float ov = v[ct] * inv;
                    if (a.outf) a.outf[(size_t)row * DIM + col] = ov;
                    if (a.outh) a.outh[(size_t)row * DIM + col] = (_Float16)ov;
                }
            }
        }
    }
}

// ---------------- launch ----------------

static inline size_t align_up(size_t v, size_t a) { return (v + a - 1) & ~(a - 1); }

extern "C" void kernel_launch(void* const* d_in, const int* in_sizes, int n_in,
                              void* d_out, int out_size, void* d_ws, size_t ws_size,
                              hipStream_t stream) {
    const float* x        = (const float*)d_in[0];
    const int* edge_index = (const int*)d_in[1];
    const int* edge_hop   = (const int*)d_in[2];
    const int* edge_type  = (const int*)d_in[3];
    const float* W_edge   = (const float*)d_in[4];
    const float* b_edge   = (const float*)d_in[5];
    const float* W_hop    = (const float*)d_in[6];
    const float* b_hop    = (const float*)d_in[7];
    float* out = (float*)d_out;

    int N = in_sizes[0] / DIM;   // 50000
    int E = in_sizes[2];         // 600000
    const int* srcA = edge_index;
    const int* dstA = edge_index + E;

    const int B1 = (E + CHUNK - 1) / CHUNK;     // 147
    const int NBKT = (N + 255) >> 8;            // 196
    const int n2 = NBKT * B1;                   // 28812

    size_t NSh = (size_t)N * DIM * sizeof(_Float16);
    size_t off = 0;
    char* wsb = (char*)d_ws;
    _Float16* xh0     = (_Float16*)(wsb + off);  off = align_up(off + NSh, 64);
    _Float16* xh1     = (_Float16*)(wsb + off);  off = align_up(off + NSh, 64);
    _Float16* xh2     = (_Float16*)(wsb + off);  off = align_up(off + NSh, 64);
    _Float16* xh3     = (_Float16*)(wsb + off);  off = align_up(off + NSh, 64);
    _Float16* Atype   = (_Float16*)(wsb + off);  off = align_up(off + 3 * NSh, 64);
    _Float16* Ahop    = (_Float16*)(wsb + off);  off = align_up(off + 7 * NSh, 64);
    _Float16* Wt      = (_Float16*)(wsb + off);  off = align_up(off + 13 * DIM * DIM * sizeof(_Float16), 64);
    int* ghist        = (int*)(wsb + off);       off = align_up(off + (size_t)n2 * 4, 64);
    int* gcur         = (int*)(wsb + off);       off = align_up(off + (size_t)(n2 + 1) * 4, 64);
    int* row_ptr      = (int*)(wsb + off);       off = align_up(off + (size_t)(N + 1) * 4, 64);
    unsigned long long* ebuf = (unsigned long long*)(wsb + off);
                                                 off = align_up(off + (size_t)E * 8, 64);
    unsigned* csr     = (unsigned*)(wsb + off);  off = align_up(off + (size_t)E * 4, 64);
    float* bias_sums  = (float*)(wsb + off);     off = align_up(off + 4 * DIM * 4, 64);
    (void)ws_size;  // ~195 MB

    // CSR build (bucketed two-pass)
    k_hist1<<<B1, 256, 0, stream>>>(dstA, E, B1, NBKT, ghist);
    k_scan_all<<<1, 1024, 0, stream>>>(ghist, n2, gcur);
    k_scat1<<<B1, 256, 0, stream>>>(srcA, dstA, edge_type, edge_hop, E, B1, NBKT, gcur, ebuf);
    k_finalize<<<NBKT, 256, 0, stream>>>(ebuf, gcur, E, B1, NBKT, N, csr, row_ptr);

    // merged conversions + bias
    const int NXB = (N * DIM / 8 + 255) / 256;   // 3125
    k_misc<<<NXB + 13 + 4, 256, 0, stream>>>(x, xh0, NXB, N * DIM,
                                             W_edge, W_hop, Wt, b_edge, b_hop, bias_sums);

    _Float16* xh_ptr[4] = { xh0, xh1, xh2, xh3 };
    const size_t NS = (size_t)N * DIM;

    for (int t = 0; t < NLAYER; ++t) {
        GatherArgs g;
        g.xt = xh_ptr[t];
        g.Atype = Atype; g.Ahop = Ahop;
        g.row_ptr = row_ptr; g.csr = csr; g.N = N;
        const int gbg = (N + 3) / 4;
        switch (t) {
            case 0: k_gather<0><<<gbg, 256, 0, stream>>>(g); break;
            case 1: k_gather<1><<<gbg, 256, 0, stream>>>(g); break;
            case 2: k_gather<2><<<gbg, 256, 0, stream>>>(g); break;
            default: k_gather<3><<<gbg, 256, 0, stream>>>(g); break;
        }

        GemmArgs m;
        m.Wt = Wt; m.xin = xh_ptr[t];
        m.bias = bias_sums + t * DIM;
        m.outf = (t == 3) ? out : nullptr;
        m.outh = (t < 3) ? xh_ptr[t + 1] : nullptr;
        m.N = N;
        const int nsub = t + 4;
        const int base = t * (t + 1) / 2;
        for (int s = 0; s < 3; ++s) { m.wsel[s] = s; m.Aslot[s] = Atype + (size_t)s * NS; }
        for (int j = 0; j <= t; ++j) {
            m.wsel[3 + j] = 3 + base + j;
            m.Aslot[3 + j] = Ahop + (size_t)PHYS[base + j] * NS;
        }
        for (int s = nsub; s < 7; ++s) { m.wsel[s] = 0; m.Aslot[s] = Atype; }

        const int gb = (N + 63) / 64;
        switch (nsub) {
            case 4: k_gemm<4><<<gb, 128, 0, stream>>>(m); break;
            case 5: k_gemm<5><<<gb, 128, 0, stream>>>(m); break;
            case 6: k_gemm<6><<<gb, 128, 0, stream>>>(m); break;
            default: k_gemm<7><<<gb, 128, 0, stream>>>(m); break;
        }
    }
}

// Round 13
// 296.505 us; speedup vs baseline: 1.1098x; 1.1098x over previous
//
#include <hip/hip_runtime.h>
#include <hip/hip_bf16.h>

#define DIM 128
#define NLAYER 4
#define CHUNK 4096     // edges per block in CSR-build pass 1

typedef _Float16 f16x8 __attribute__((ext_vector_type(8)));
typedef _Float16 f16x2 __attribute__((ext_vector_type(2)));
typedef float f32x4 __attribute__((ext_vector_type(4)));

// Physical slot map for the 10 logical hop slots (ring allocation, peak live = 6).
static constexpr int PHYS[10] = {0, 4, 1, 0, 5, 2, 1, 4, 6, 3};

// ============ CSR build: bucketed two-pass, coalesced final writes ============

__global__ __launch_bounds__(256) void k_hist1(const int* __restrict__ dst, int E,
                                               int B1, int NBKT, int* __restrict__ ghist) {
    __shared__ int h[256];
    h[threadIdx.x] = 0;
    __syncthreads();
    const int base = blockIdx.x * CHUNK;
    #pragma unroll
    for (int i = 0; i < CHUNK / 256; ++i) {
        int e = base + i * 256 + threadIdx.x;
        if (e < E) atomicAdd(&h[dst[e] >> 8], 1);
    }
    __syncthreads();
    if (threadIdx.x < NBKT) ghist[threadIdx.x * B1 + blockIdx.x] = h[threadIdx.x];
}

// hierarchical scan: per-block inclusive (k_scan1) -> block-sum exclusive (k_scan2)
// -> broadcast to exclusive output (k_scan3b). ~10 us total at n=28812.

__global__ __launch_bounds__(1024) void k_scan1(const int* __restrict__ in, int n,
                                                int* __restrict__ partial,
                                                int* __restrict__ blockSums) {
    __shared__ int sd[1024];
    int tid = threadIdx.x;
    int i = blockIdx.x * 1024 + tid;
    int v = (i < n) ? in[i] : 0;
    sd[tid] = v;
    __syncthreads();
    for (int off = 1; off < 1024; off <<= 1) {
        int t = (tid >= off) ? sd[tid - off] : 0;
        __syncthreads();
        sd[tid] += t;
        __syncthreads();
    }
    if (i < n) partial[i] = sd[tid];
    if (tid == 1023) blockSums[blockIdx.x] = sd[1023];
}

__global__ void k_scan2(int* __restrict__ bs, int nb) {   // nb <= 64
    int lane = threadIdx.x;
    int v = (lane < nb) ? bs[lane] : 0;
    for (int off = 1; off < 64; off <<= 1) {
        int t = __shfl_up(v, off, 64);
        if (lane >= off) v += t;
    }
    int ex = __shfl_up(v, 1, 64);
    if (lane == 0) ex = 0;
    if (lane < nb) bs[lane] = ex;
}

__global__ __launch_bounds__(1024) void k_scan3b(const int* __restrict__ partial,
                                                 const int* __restrict__ in,
                                                 const int* __restrict__ bs, int n,
                                                 int* __restrict__ outEx) {
    int i = blockIdx.x * blockDim.x + threadIdx.x;
    if (i < n) outEx[i] = partial[i] + bs[i >> 10] - in[i];   // exclusive
    if (i == 0) outEx[n] = 0;  // overwritten below; n-th set by last block
    if (i == n - 1) outEx[n] = partial[i] + bs[i >> 10];
}

__global__ __launch_bounds__(256) void k_scat1(const int* __restrict__ srcA,
                                               const int* __restrict__ dstA,
                                               const int* __restrict__ typA,
                                               const int* __restrict__ hopA,
                                               int E, int B1, int NBKT,
                                               const int* __restrict__ gcur,
                                               unsigned long long* __restrict__ ebuf) {
    __shared__ int cur[256];
    if (threadIdx.x < NBKT) cur[threadIdx.x] = gcur[threadIdx.x * B1 + blockIdx.x];
    __syncthreads();
    const int base = blockIdx.x * CHUNK;
    #pragma unroll
    for (int i = 0; i < CHUNK / 256; ++i) {
        int e = base + i * 256 + threadIdx.x;
        if (e < E) {
            int d = dstA[e];
            unsigned w = ((unsigned)srcA[e] << 8) | ((unsigned)typA[e] << 24)
                       | ((unsigned)hopA[e] << 26);
            int p = atomicAdd(&cur[d >> 8], 1);
            ebuf[p] = ((unsigned long long)(unsigned)d << 32) | w;
        }
    }
}

__global__ __launch_bounds__(256) void k_finalize(const unsigned long long* __restrict__ ebuf,
                                                  const int* __restrict__ gcur,
                                                  int E, int B1, int NBKT, int N,
                                                  unsigned* __restrict__ csr,
                                                  int* __restrict__ row_ptr) {
    __shared__ int cnt[256], sd[256], off2[256];
    __shared__ unsigned stg[8192];
    const int bkt = blockIdx.x, tid = threadIdx.x;
    const int base = gcur[bkt * B1];
    const int endv = (bkt + 1 < NBKT) ? gcur[(bkt + 1) * B1] : E;
    const int n = endv - base;

    cnt[tid] = 0;
    __syncthreads();
    for (int i = tid; i < n; i += 256)
        atomicAdd(&cnt[(int)((ebuf[base + i] >> 32) & 255)], 1);
    __syncthreads();

    sd[tid] = cnt[tid];
    __syncthreads();
    for (int o = 1; o < 256; o <<= 1) {
        int t = (tid >= o) ? sd[tid - o] : 0;
        __syncthreads();
        sd[tid] += t;
        __syncthreads();
    }
    const int ex = (tid > 0) ? sd[tid - 1] : 0;
    off2[tid] = ex;
    const int node = bkt * 256 + tid;
    if (node < N) row_ptr[node] = base + ex;
    if (bkt == NBKT - 1 && tid == 0) row_ptr[N] = E;
    __syncthreads();

    for (int i = tid; i < n; i += 256) {
        const unsigned long long ld = ebuf[base + i];
        const int r = atomicAdd(&off2[(int)((ld >> 32) & 255)], 1);
        stg[r] = (unsigned)ld;
    }
    __syncthreads();
    for (int i = tid; i < n; i += 256) csr[base + i] = stg[i];
}

// ---------------- merged conversions + bias: blockIdx-sectioned ----------------
// blocks [0, NXB): convX ; [NXB, NXB+13): convW ; [NXB+13, NXB+17): bias

__global__ __launch_bounds__(256) void k_misc(const float* __restrict__ x,
                                              _Float16* __restrict__ xh0, int NXB, int nElem,
                                              const float* __restrict__ W_edge,
                                              const float* __restrict__ W_hop,
                                              _Float16* __restrict__ Wt,
                                              const float* __restrict__ b_edge,
                                              const float* __restrict__ b_hop,
                                              float* __restrict__ bias_sums) {
    const int b = blockIdx.x, tid = threadIdx.x;
    if (b < NXB) {
        int i = (b * 256 + tid) * 8;
        if (i >= nElem) return;
        float4 a0 = ((const float4*)(x + i))[0];
        float4 a1 = ((const float4*)(x + i))[1];
        f16x8 o;
        o[0] = (_Float16)a0.x; o[1] = (_Float16)a0.y; o[2] = (_Float16)a0.z; o[3] = (_Float16)a0.w;
        o[4] = (_Float16)a1.x; o[5] = (_Float16)a1.y; o[6] = (_Float16)a1.z; o[7] = (_Float16)a1.w;
        *(f16x8*)(xh0 + i) = o;
    } else if (b < NXB + 13) {
        int s = b - NXB;
        const float* src = (s < 3) ? (W_edge + (size_t)s * DIM * DIM)
                                   : (W_hop + (size_t)(s - 3) * DIM * DIM);
        _Float16* dstp = Wt + (size_t)s * DIM * DIM;
        for (int it = 0; it < 64; ++it) {
            int e = it * 256 + tid;
            int n = e >> 7, k = e & 127;
            dstp[e] = (_Float16)src[k * DIM + n];
        }
    } else {
        if (tid >= DIM) return;
        int t = b - NXB - 13;
        float s = b_edge[tid] + b_edge[DIM + tid] + b_edge[2 * DIM + tid];
        int base = t * (t + 1) / 2;
        for (int k = 1; k <= t + 1; ++k) s += b_hop[(base + k - 1) * DIM + tid];
        bias_sums[t * DIM + tid] = s;
    }
}

// -------- phase 1: single-pass gather; future hop slots accumulated now --------
// 256-thr blocks, 1 node/wave; node pinned to SGPR via readfirstlane so the csr
// words scalarize (s_load + uniform branches) while 4 waves share one WG slot.

struct GatherArgs {
    const _Float16* __restrict__ xt;    // xh[TAU]
    _Float16* __restrict__ Atype;       // [3][N][128]
    _Float16* __restrict__ Ahop;        // [7][N][128] physical ring slots
    const int* __restrict__ row_ptr;
    const unsigned* __restrict__ csr;
    int N;
};

template <int TAU>
__global__ __launch_bounds__(256) void k_gather(GatherArgs a) {
    const int lane = threadIdx.x & 63;
    const int node = __builtin_amdgcn_readfirstlane(blockIdx.x * 4 + (threadIdx.x >> 6));
    if (node >= a.N) return;
    const size_t NS = (size_t)a.N * DIM;

    const char* xtl = (const char*)a.xt + lane * 4;

    float t0x = 0, t0y = 0, t1x = 0, t1y = 0, t2x = 0, t2y = 0;
    float h1x = 0, h1y = 0, h2x = 0, h2y = 0, h3x = 0, h3y = 0, h4x = 0, h4y = 0;

    const int e0 = a.row_ptr[node], e1 = a.row_ptr[node + 1];
    int e = e0;

    #define ACCUM(m, v)                                                        \
        {                                                                      \
            const int typ = (int)((m) >> 24) & 3;                              \
            const int hop = (int)((m) >> 26);                                  \
            const float vx = (float)(v)[0], vy = (float)(v)[1];                \
            if (typ == 0)      { t0x += vx; t0y += vy; }                       \
            else if (typ == 1) { t1x += vx; t1y += vy; }                       \
            else               { t2x += vx; t2y += vy; }                       \
            if (hop == 1)                    { h1x += vx; h1y += vy; }         \
            else if (TAU <= 2 && hop == 2)   { h2x += vx; h2y += vy; }         \
            else if (TAU <= 1 && hop == 3)   { h3x += vx; h3y += vy; }         \
            else if (TAU == 0 && hop == 4)   { h4x += vx; h4y += vy; }         \
        }

    for (; e + 8 <= e1; e += 8) {
        unsigned mm[8];
        #pragma unroll
        for (int j = 0; j < 8; ++j) mm[j] = a.csr[e + j];
        f16x2 vv[8];
        #pragma unroll
        for (int j = 0; j < 8; ++j)
            vv[j] = *(const f16x2*)(xtl + (mm[j] & 0xFFFFFF));
        #pragma unroll
        for (int j = 0; j < 8; ++j) ACCUM(mm[j], vv[j])
    }
    for (; e + 4 <= e1; e += 4) {
        unsigned mm[4];
        #pragma unroll
        for (int j = 0; j < 4; ++j) mm[j] = a.csr[e + j];
        f16x2 vv[4];
        #pragma unroll
        for (int j = 0; j < 4; ++j)
            vv[j] = *(const f16x2*)(xtl + (mm[j] & 0xFFFFFF));
        #pragma unroll
        for (int j = 0; j < 4; ++j) ACCUM(mm[j], vv[j])
    }
    for (; e < e1; ++e) {
        const unsigned m = a.csr[e];
        const f16x2 v = *(const f16x2*)(xtl + (m & 0xFFFFFF));
        ACCUM(m, v)
    }
    #undef ACCUM

    _Float16* tb = a.Atype + (size_t)node * DIM;
    f16x2 o;
    o[0] = (_Float16)t0x; o[1] = (_Float16)t0y; ((f16x2*)(tb + 0 * NS))[lane] = o;
    o[0] = (_Float16)t1x; o[1] = (_Float16)t1y; ((f16x2*)(tb + 1 * NS))[lane] = o;
    o[0] = (_Float16)t2x; o[1] = (_Float16)t2y; ((f16x2*)(tb + 2 * NS))[lane] = o;

    _Float16* hb = a.Ahop + (size_t)node * DIM;
    {
        constexpr int P1 = PHYS[(TAU * (TAU + 1)) / 2];
        o[0] = (_Float16)h1x; o[1] = (_Float16)h1y; ((f16x2*)(hb + (size_t)P1 * NS))[lane] = o;
    }
    if constexpr (TAU <= 2) {
        constexpr int P2 = PHYS[((TAU + 1) * (TAU + 2)) / 2 + 1];
        o[0] = (_Float16)h2x; o[1] = (_Float16)h2y; ((f16x2*)(hb + (size_t)P2 * NS))[lane] = o;
    }
    if constexpr (TAU <= 1) {
        constexpr int P3 = PHYS[((TAU + 2) * (TAU + 3)) / 2 + 2];
        o[0] = (_Float16)h3x; o[1] = (_Float16)h3y; ((f16x2*)(hb + (size_t)P3 * NS))[lane] = o;
    }
    if constexpr (TAU == 0) {
        constexpr int P4 = PHYS[9];
        o[0] = (_Float16)h4x; o[1] = (_Float16)h4y; ((f16x2*)(hb + (size_t)P4 * NS))[lane] = o;
    }
}

// -------- phase 2: C = sum_s A_s @ W_s, fused bias+relu+residual+L2norm --------

struct GemmArgs {
    const _Float16* Aslot[7];
    const _Float16* Wt;
    const _Float16* xin;
    const float* bias;
    float* outf;
    _Float16* outh;
    int N;
    int wsel[7];
};

template <int NSUB>
__global__ __launch_bounds__(128, 2) void k_gemm(GemmArgs a) {
    __shared__ __align__(16) _Float16 Wlds[DIM * DIM];   // 32 KB, swizzled
    const int tid = threadIdx.x, wv = tid >> 6, lane = tid & 63;
    const int rowBase = blockIdx.x * 64 + wv * 32;
    const int lr = lane & 15, lg = lane >> 4;

    int r0 = rowBase + lr, r1 = rowBase + 16 + lr;
    if (r0 >= a.N) r0 = a.N - 1;
    if (r1 >= a.N) r1 = a.N - 1;

    f32x4 acc[2][8];
    #pragma unroll
    for (int rt = 0; rt < 2; ++rt)
        #pragma unroll
        for (int ct = 0; ct < 8; ++ct)
            acc[rt][ct] = (f32x4){0.f, 0.f, 0.f, 0.f};

    const int sw = (lr & 7) << 4;

    {
        const _Float16* Ws = a.Wt + (size_t)a.wsel[0] * (DIM * DIM);
        f16x8 w[16];
        #pragma unroll
        for (int i = 0; i < 16; ++i)
            w[i] = *(const f16x8*)((const char*)Ws + i * 2048 + tid * 16);
        #pragma unroll
        for (int i = 0; i < 16; ++i) {
            const int p = i * 2048 + tid * 16;
            const int q = p ^ (((p >> 8) & 7) << 4);
            *(f16x8*)((char*)Wlds + q) = w[i];
        }
    }
    f16x8 afA[2][4], afB[2][4];
    #pragma unroll
    for (int ks = 0; ks < 4; ++ks) {
        afA[0][ks] = *(const f16x8*)(a.Aslot[0] + (size_t)r0 * DIM + ks * 32 + lg * 8);
        afB[0][ks] = *(const f16x8*)(a.Aslot[0] + (size_t)r1 * DIM + ks * 32 + lg * 8);
    }
    __syncthreads();

    #pragma unroll
    for (int s = 0; s < NSUB; ++s) {
        const int cur = s & 1, nxt = cur ^ 1;
        f16x8 w[16];
        if (s + 1 < NSUB) {
            const _Float16* Wn = a.Wt + (size_t)a.wsel[s + 1] * (DIM * DIM);
            #pragma unroll
            for (int i = 0; i < 16; ++i)
                w[i] = *(const f16x8*)((const char*)Wn + i * 2048 + tid * 16);
            const _Float16* An = a.Aslot[s + 1];
            #pragma unroll
            for (int ks = 0; ks < 4; ++ks) {
                afA[nxt][ks] = *(const f16x8*)(An + (size_t)r0 * DIM + ks * 32 + lg * 8);
                afB[nxt][ks] = *(const f16x8*)(An + (size_t)r1 * DIM + ks * 32 + lg * 8);
            }
        }
        #pragma unroll
        for (int ks = 0; ks < 4; ++ks) {
            const int cb = (ks * 32 + lg * 8) * 2;
            #pragma unroll
            for (int ct = 0; ct < 8; ++ct) {
                const int addr = (ct * 16 + lr) * 256 + (cb ^ sw);
                const f16x8 bf = *(const f16x8*)((const char*)Wlds + addr);
                acc[0][ct] = __builtin_amdgcn_mfma_f32_16x16x32_f16(afA[cur][ks], bf, acc[0][ct], 0, 0, 0);
                acc[1][ct] = __builtin_amdgcn_mfma_f32_16x16x32_f16(afB[cur][ks], bf, acc[1][ct], 0, 0, 0);
            }
        }
        __syncthreads();
        if (s + 1 < NSUB) {
            #pragma unroll
            for (int i = 0; i < 16; ++i) {
                const int p = i * 2048 + tid * 16;
                const int q = p ^ (((p >> 8) & 7) << 4);
                *(f16x8*)((char*)Wlds + q) = w[i];
            }
            __syncthreads();
        }
    }

    float bv[8];
    #pragma unroll
    for (int ct = 0; ct < 8; ++ct) bv[ct] = a.bias[ct * 16 + lr];

    #pragma unroll
    for (int rt = 0; rt < 2; ++rt) {
        #pragma unroll
        for (int rg = 0; rg < 4; ++rg) {
            const int row = rowBase + rt * 16 + lg * 4 + rg;
            const int rr = (row < a.N) ? row : a.N - 1;
            float v[8];
            float ss = 0.f;
            #pragma unroll
            for (int ct = 0; ct < 8; ++ct) {
                const float xval = (float)a.xin[(size_t)rr * DIM + ct * 16 + lr];
                const float tv = fmaxf(acc[rt][ct][rg] + bv[ct], 0.f) + xval;
                v[ct] = tv;
                ss += tv * tv;
            }
            ss += __shfl_xor(ss, 1, 64);
            ss += __shfl_xor(ss, 2, 64);
            ss += __shfl_xor(ss, 4, 64);
            ss += __shfl_xor(ss, 8, 64);
            const float inv = 1.f / fmaxf(sqrtf(ss), 1e-12f);
            if (row < a.N) {
                #pragma unroll
                for (int ct = 0; ct < 8; ++ct) {
                    const int col = ct * 16 + lr;
                    const float ov = v[ct] * inv;
                    if (a.outf) a.outf[(size_t)row * DIM + col] = ov;
                    if (a.outh) a.outh[(size_t)row * DIM + col] = (_Float16)ov;
                }
            }
        }
    }
}

// ---------------- launch ----------------

static inline size_t align_up(size_t v, size_t a) { return (v + a - 1) & ~(a - 1); }

extern "C" void kernel_launch(void* const* d_in, const int* in_sizes, int n_in,
                              void* d_out, int out_size, void* d_ws, size_t ws_size,
                              hipStream_t stream) {
    const float* x        = (const float*)d_in[0];
    const int* edge_index = (const int*)d_in[1];
    const int* edge_hop   = (const int*)d_in[2];
    const int* edge_type  = (const int*)d_in[3];
    const float* W_edge   = (const float*)d_in[4];
    const float* b_edge   = (const float*)d_in[5];
    const float* W_hop    = (const float*)d_in[6];
    const float* b_hop    = (const float*)d_in[7];
    float* out = (float*)d_out;

    int N = in_sizes[0] / DIM;   // 50000
    int E = in_sizes[2];         // 600000
    const int* srcA = edge_index;
    const int* dstA = edge_index + E;

    const int B1 = (E + CHUNK - 1) / CHUNK;     // 147
    const int NBKT = (N + 255) >> 8;            // 196
    const int n2 = NBKT * B1;                   // 28812

    size_t NSh = (size_t)N * DIM * sizeof(_Float16);
    size_t off = 0;
    char* wsb = (char*)d_ws;
    _Float16* xh0     = (_Float16*)(wsb + off);  off = align_up(off + NSh, 64);
    _Float16* xh1     = (_Float16*)(wsb + off);  off = align_up(off + NSh, 64);
    _Float16* xh2     = (_Float16*)(wsb + off);  off = align_up(off + NSh, 64);
    _Float16* xh3     = (_Float16*)(wsb + off);  off = align_up(off + NSh, 64);
    _Float16* Atype   = (_Float16*)(wsb + off);  off = align_up(off + 3 * NSh, 64);
    _Float16* Ahop    = (_Float16*)(wsb + off);  off = align_up(off + 7 * NSh, 64);
    _Float16* Wt      = (_Float16*)(wsb + off);  off = align_up(off + 13 * DIM * DIM * sizeof(_Float16), 64);
    int* ghist        = (int*)(wsb + off);       off = align_up(off + (size_t)n2 * 4, 64);
    int* partial      = (int*)(wsb + off);       off = align_up(off + (size_t)n2 * 4, 64);
    int* blockSums    = (int*)(wsb + off);       off = align_up(off + 64 * 4, 64);
    int* gcur         = (int*)(wsb + off);       off = align_up(off + (size_t)(n2 + 1) * 4, 64);
    int* row_ptr      = (int*)(wsb + off);       off = align_up(off + (size_t)(N + 1) * 4, 64);
    unsigned long long* ebuf = (unsigned long long*)(wsb + off);
                                                 off = align_up(off + (size_t)E * 8, 64);
    unsigned* csr     = (unsigned*)(wsb + off);  off = align_up(off + (size_t)E * 4, 64);
    float* bias_sums  = (float*)(wsb + off);     off = align_up(off + 4 * DIM * 4, 64);
    (void)ws_size;  // ~195 MB

    // CSR build (bucketed two-pass, hierarchical scan)
    k_hist1<<<B1, 256, 0, stream>>>(dstA, E, B1, NBKT, ghist);
    int nb2 = (n2 + 1023) / 1024;   // 29
    k_scan1<<<nb2, 1024, 0, stream>>>(ghist, n2, partial, blockSums);
    k_scan2<<<1, 64, 0, stream>>>(blockSums, nb2);
    k_scan3b<<<nb2, 1024, 0, stream>>>(partial, ghist, blockSums, n2, gcur);
    k_scat1<<<B1, 256, 0, stream>>>(srcA, dstA, edge_type, edge_hop, E, B1, NBKT, gcur, ebuf);
    k_finalize<<<NBKT, 256, 0, stream>>>(ebuf, gcur, E, B1, NBKT, N, csr, row_ptr);

    // merged conversions + bias
    const int NXB = (N * DIM / 8 + 255) / 256;   // 3125
    k_misc<<<NXB + 13 + 4, 256, 0, stream>>>(x, xh0, NXB, N * DIM,
                                             W_edge, W_hop, Wt, b_edge, b_hop, bias_sums);

    _Float16* xh_ptr[4] = { xh0, xh1, xh2, xh3 };
    const size_t NS = (size_t)N * DIM;

    for (int t = 0; t < NLAYER; ++t) {
        GatherArgs g;
        g.xt = xh_ptr[t];
        g.Atype = Atype; g.Ahop = Ahop;
        g.row_ptr = row_ptr; g.csr = csr; g.N = N;
        const int gbg = (N + 3) / 4;
        switch (t) {
            case 0: k_gather<0><<<gbg, 256, 0, stream>>>(g); break;
            case 1: k_gather<1><<<gbg, 256, 0, stream>>>(g); break;
            case 2: k_gather<2><<<gbg, 256, 0, stream>>>(g); break;
            default: k_gather<3><<<gbg, 256, 0, stream>>>(g); break;
        }

        GemmArgs m;
        m.Wt = Wt; m.xin = xh_ptr[t];
        m.bias = bias_sums + t * DIM;
        m.outf = (t == 3) ? out : nullptr;
        m.outh = (t < 3) ? xh_ptr[t + 1] : nullptr;
        m.N = N;
        const int nsub = t + 4;
        const int base = t * (t + 1) / 2;
        for (int s = 0; s < 3; ++s) { m.wsel[s] = s; m.Aslot[s] = Atype + (size_t)s * NS; }
        for (int j = 0; j <= t; ++j) {
            m.wsel[3 + j] = 3 + base + j;
            m.Aslot[3 + j] = Ahop + (size_t)PHYS[base + j] * NS;
        }
        for (int s = nsub; s < 7; ++s) { m.wsel[s] = 0; m.Aslot[s] = Atype; }

        const int gb = (N + 63) / 64;
        switch (nsub) {
            case 4: k_gemm<4><<<gb, 128, 0, stream>>>(m); break;
            case 5: k_gemm<5><<<gb, 128, 0, stream>>>(m); break;
            case 6: k_gemm<6><<<gb, 128, 0, stream>>>(m); break;
            default: k_gemm<7><<<gb, 128, 0, stream>>>(m); break;
        }
    }
}

// Round 14
// 292.979 us; speedup vs baseline: 1.1232x; 1.0120x over previous
//
#include <hip/hip_runtime.h>
#include <hip/hip_bf16.h>

#define DIM 128
#define NLAYER 4
#define CHUNK 4096     // edges per block in CSR-build pass 1

typedef _Float16 f16x8 __attribute__((ext_vector_type(8)));
typedef _Float16 f16x2 __attribute__((ext_vector_type(2)));
typedef float f32x4 __attribute__((ext_vector_type(4)));

// Physical slot map for the 10 logical hop slots (ring allocation, peak live = 6).
static constexpr int PHYS[10] = {0, 4, 1, 0, 5, 2, 1, 4, 6, 3};

// ============ CSR build: bucketed two-pass, coalesced final writes ============

__global__ __launch_bounds__(256) void k_hist1(const int* __restrict__ dst, int E,
                                               int B1, int NBKT, int* __restrict__ ghist) {
    __shared__ int h[256];
    h[threadIdx.x] = 0;
    __syncthreads();
    const int base = blockIdx.x * CHUNK;
    #pragma unroll
    for (int i = 0; i < CHUNK / 256; ++i) {
        int e = base + i * 256 + threadIdx.x;
        if (e < E) atomicAdd(&h[dst[e] >> 8], 1);
    }
    __syncthreads();
    if (threadIdx.x < NBKT) ghist[threadIdx.x * B1 + blockIdx.x] = h[threadIdx.x];
}

// hierarchical scan: per-block inclusive -> block-sum exclusive -> broadcast

__global__ __launch_bounds__(1024) void k_scan1(const int* __restrict__ in, int n,
                                                int* __restrict__ partial,
                                                int* __restrict__ blockSums) {
    __shared__ int sd[1024];
    int tid = threadIdx.x;
    int i = blockIdx.x * 1024 + tid;
    int v = (i < n) ? in[i] : 0;
    sd[tid] = v;
    __syncthreads();
    for (int off = 1; off < 1024; off <<= 1) {
        int t = (tid >= off) ? sd[tid - off] : 0;
        __syncthreads();
        sd[tid] += t;
        __syncthreads();
    }
    if (i < n) partial[i] = sd[tid];
    if (tid == 1023) blockSums[blockIdx.x] = sd[1023];
}

__global__ void k_scan2(int* __restrict__ bs, int nb) {   // nb <= 64
    int lane = threadIdx.x;
    int v = (lane < nb) ? bs[lane] : 0;
    for (int off = 1; off < 64; off <<= 1) {
        int t = __shfl_up(v, off, 64);
        if (lane >= off) v += t;
    }
    int ex = __shfl_up(v, 1, 64);
    if (lane == 0) ex = 0;
    if (lane < nb) bs[lane] = ex;
}

__global__ __launch_bounds__(1024) void k_scan3b(const int* __restrict__ partial,
                                                 const int* __restrict__ in,
                                                 const int* __restrict__ bs, int n,
                                                 int* __restrict__ outEx) {
    int i = blockIdx.x * blockDim.x + threadIdx.x;
    if (i < n) outEx[i] = partial[i] + bs[i >> 10] - in[i];   // exclusive
    if (i == n - 1) outEx[n] = partial[i] + bs[i >> 10];
}

__global__ __launch_bounds__(256) void k_scat1(const int* __restrict__ srcA,
                                               const int* __restrict__ dstA,
                                               const int* __restrict__ typA,
                                               const int* __restrict__ hopA,
                                               int E, int B1, int NBKT,
                                               const int* __restrict__ gcur,
                                               unsigned long long* __restrict__ ebuf) {
    __shared__ int cur[256];
    if (threadIdx.x < NBKT) cur[threadIdx.x] = gcur[threadIdx.x * B1 + blockIdx.x];
    __syncthreads();
    const int base = blockIdx.x * CHUNK;
    #pragma unroll
    for (int i = 0; i < CHUNK / 256; ++i) {
        int e = base + i * 256 + threadIdx.x;
        if (e < E) {
            int d = dstA[e];
            unsigned w = ((unsigned)srcA[e] << 8) | ((unsigned)typA[e] << 24)
                       | ((unsigned)hopA[e] << 26);
            int p = atomicAdd(&cur[d >> 8], 1);
            ebuf[p] = ((unsigned long long)(unsigned)d << 32) | w;
        }
    }
}

__global__ __launch_bounds__(256) void k_finalize(const unsigned long long* __restrict__ ebuf,
                                                  const int* __restrict__ gcur,
                                                  int E, int B1, int NBKT, int N,
                                                  unsigned* __restrict__ csr,
                                                  int* __restrict__ row_ptr) {
    __shared__ int cnt[256], sd[256], off2[256];
    __shared__ unsigned stg[8192];
    const int bkt = blockIdx.x, tid = threadIdx.x;
    const int base = gcur[bkt * B1];
    const int endv = (bkt + 1 < NBKT) ? gcur[(bkt + 1) * B1] : E;
    const int n = endv - base;

    cnt[tid] = 0;
    __syncthreads();
    for (int i = tid; i < n; i += 256)
        atomicAdd(&cnt[(int)((ebuf[base + i] >> 32) & 255)], 1);
    __syncthreads();

    sd[tid] = cnt[tid];
    __syncthreads();
    for (int o = 1; o < 256; o <<= 1) {
        int t = (tid >= o) ? sd[tid - o] : 0;
        __syncthreads();
        sd[tid] += t;
        __syncthreads();
    }
    const int ex = (tid > 0) ? sd[tid - 1] : 0;
    off2[tid] = ex;
    const int node = bkt * 256 + tid;
    if (node < N) row_ptr[node] = base + ex;
    if (bkt == NBKT - 1 && tid == 0) row_ptr[N] = E;
    __syncthreads();

    for (int i = tid; i < n; i += 256) {
        const unsigned long long ld = ebuf[base + i];
        const int r = atomicAdd(&off2[(int)((ld >> 32) & 255)], 1);
        stg[r] = (unsigned)ld;
    }
    __syncthreads();
    for (int i = tid; i < n; i += 256) csr[base + i] = stg[i];
}

// ---------------- merged conversions + bias: blockIdx-sectioned ----------------

__global__ __launch_bounds__(256) void k_misc(const float* __restrict__ x,
                                              _Float16* __restrict__ xh0, int NXB, int nElem,
                                              const float* __restrict__ W_edge,
                                              const float* __restrict__ W_hop,
                                              _Float16* __restrict__ Wt,
                                              const float* __restrict__ b_edge,
                                              const float* __restrict__ b_hop,
                                              float* __restrict__ bias_sums) {
    const int b = blockIdx.x, tid = threadIdx.x;
    if (b < NXB) {
        int i = (b * 256 + tid) * 8;
        if (i >= nElem) return;
        float4 a0 = ((const float4*)(x + i))[0];
        float4 a1 = ((const float4*)(x + i))[1];
        f16x8 o;
        o[0] = (_Float16)a0.x; o[1] = (_Float16)a0.y; o[2] = (_Float16)a0.z; o[3] = (_Float16)a0.w;
        o[4] = (_Float16)a1.x; o[5] = (_Float16)a1.y; o[6] = (_Float16)a1.z; o[7] = (_Float16)a1.w;
        *(f16x8*)(xh0 + i) = o;
    } else if (b < NXB + 13) {
        int s = b - NXB;
        const float* src = (s < 3) ? (W_edge + (size_t)s * DIM * DIM)
                                   : (W_hop + (size_t)(s - 3) * DIM * DIM);
        _Float16* dstp = Wt + (size_t)s * DIM * DIM;
        for (int it = 0; it < 64; ++it) {
            int e = it * 256 + tid;
            int n = e >> 7, k = e & 127;
            dstp[e] = (_Float16)src[k * DIM + n];
        }
    } else {
        if (tid >= DIM) return;
        int t = b - NXB - 13;
        float s = b_edge[tid] + b_edge[DIM + tid] + b_edge[2 * DIM + tid];
        int base = t * (t + 1) / 2;
        for (int k = 1; k <= t + 1; ++k) s += b_hop[(base + k - 1) * DIM + tid];
        bias_sums[t * DIM + tid] = s;
    }
}

// -------- phase 1: single-pass gather; future hop slots accumulated now --------

struct GatherArgs {
    const _Float16* __restrict__ xt;
    _Float16* __restrict__ Atype;       // [3][N][128]
    _Float16* __restrict__ Ahop;        // [7][N][128] physical ring slots
    const int* __restrict__ row_ptr;
    const unsigned* __restrict__ csr;
    int N;
};

template <int TAU>
__global__ __launch_bounds__(256) void k_gather(GatherArgs a) {
    const int lane = threadIdx.x & 63;
    const int node = __builtin_amdgcn_readfirstlane(blockIdx.x * 4 + (threadIdx.x >> 6));
    if (node >= a.N) return;
    const size_t NS = (size_t)a.N * DIM;

    const char* xtl = (const char*)a.xt + lane * 4;

    float t0x = 0, t0y = 0, t1x = 0, t1y = 0, t2x = 0, t2y = 0;
    float h1x = 0, h1y = 0, h2x = 0, h2y = 0, h3x = 0, h3y = 0, h4x = 0, h4y = 0;

    const int e0 = a.row_ptr[node], e1 = a.row_ptr[node + 1];
    int e = e0;

    #define ACCUM(m, v)                                                        \
        {                                                                      \
            const int typ = (int)((m) >> 24) & 3;                              \
            const int hop = (int)((m) >> 26);                                  \
            const float vx = (float)(v)[0], vy = (float)(v)[1];                \
            if (typ == 0)      { t0x += vx; t0y += vy; }                       \
            else if (typ == 1) { t1x += vx; t1y += vy; }                       \
            else               { t2x += vx; t2y += vy; }                       \
            if (hop == 1)                    { h1x += vx; h1y += vy; }         \
            else if (TAU <= 2 && hop == 2)   { h2x += vx; h2y += vy; }         \
            else if (TAU <= 1 && hop == 3)   { h3x += vx; h3y += vy; }         \
            else if (TAU == 0 && hop == 4)   { h4x += vx; h4y += vy; }         \
        }

    for (; e + 8 <= e1; e += 8) {
        unsigned mm[8];
        #pragma unroll
        for (int j = 0; j < 8; ++j) mm[j] = a.csr[e + j];
        f16x2 vv[8];
        #pragma unroll
        for (int j = 0; j < 8; ++j)
            vv[j] = *(const f16x2*)(xtl + (mm[j] & 0xFFFFFF));
        #pragma unroll
        for (int j = 0; j < 8; ++j) ACCUM(mm[j], vv[j])
    }
    for (; e + 4 <= e1; e += 4) {
        unsigned mm[4];
        #pragma unroll
        for (int j = 0; j < 4; ++j) mm[j] = a.csr[e + j];
        f16x2 vv[4];
        #pragma unroll
        for (int j = 0; j < 4; ++j)
            vv[j] = *(const f16x2*)(xtl + (mm[j] & 0xFFFFFF));
        #pragma unroll
        for (int j = 0; j < 4; ++j) ACCUM(mm[j], vv[j])
    }
    for (; e < e1; ++e) {
        const unsigned m = a.csr[e];
        const f16x2 v = *(const f16x2*)(xtl + (m & 0xFFFFFF));
        ACCUM(m, v)
    }
    #undef ACCUM

    _Float16* tb = a.Atype + (size_t)node * DIM;
    f16x2 o;
    o[0] = (_Float16)t0x; o[1] = (_Float16)t0y; ((f16x2*)(tb + 0 * NS))[lane] = o;
    o[0] = (_Float16)t1x; o[1] = (_Float16)t1y; ((f16x2*)(tb + 1 * NS))[lane] = o;
    o[0] = (_Float16)t2x; o[1] = (_Float16)t2y; ((f16x2*)(tb + 2 * NS))[lane] = o;

    _Float16* hb = a.Ahop + (size_t)node * DIM;
    {
        constexpr int P1 = PHYS[(TAU * (TAU + 1)) / 2];
        o[0] = (_Float16)h1x; o[1] = (_Float16)h1y; ((f16x2*)(hb + (size_t)P1 * NS))[lane] = o;
    }
    if constexpr (TAU <= 2) {
        constexpr int P2 = PHYS[((TAU + 1) * (TAU + 2)) / 2 + 1];
        o[0] = (_Float16)h2x; o[1] = (_Float16)h2y; ((f16x2*)(hb + (size_t)P2 * NS))[lane] = o;
    }
    if constexpr (TAU <= 1) {
        constexpr int P3 = PHYS[((TAU + 2) * (TAU + 3)) / 2 + 2];
        o[0] = (_Float16)h3x; o[1] = (_Float16)h3y; ((f16x2*)(hb + (size_t)P3 * NS))[lane] = o;
    }
    if constexpr (TAU == 0) {
        constexpr int P4 = PHYS[9];
        o[0] = (_Float16)h4x; o[1] = (_Float16)h4y; ((f16x2*)(hb + (size_t)P4 * NS))[lane] = o;
    }
}

// -------- phase 2: C = sum_s A_s @ W_s, fused bias+relu+residual+L2norm --------
// 256-thr blocks, 4 waves x 16 rows (W now in LDS so small waves are fine);
// ~116 VGPR -> 16 waves/CU VGPR-wise vs 8 for the old 200-VGPR 32-row shape.

struct GemmArgs {
    const _Float16* Aslot[7];
    const _Float16* Wt;
    const _Float16* xin;
    const float* bias;
    float* outf;
    _Float16* outh;
    int N;
    int wsel[7];
};

template <int NSUB>
__global__ __launch_bounds__(256, 4) void k_gemm(GemmArgs a) {
    __shared__ __align__(16) _Float16 Wlds[DIM * DIM];   // 32 KB, swizzled
    const int tid = threadIdx.x, wv = tid >> 6, lane = tid & 63;
    const int rowBase = blockIdx.x * 64 + wv * 16;
    const int lr = lane & 15, lg = lane >> 4;

    int r = rowBase + lr;
    if (r >= a.N) r = a.N - 1;

    f32x4 acc[8];
    #pragma unroll
    for (int ct = 0; ct < 8; ++ct) acc[ct] = (f32x4){0.f, 0.f, 0.f, 0.f};

    const int sw = (lr & 7) << 4;   // read-side XOR

    // prologue: stage W[wsel[0]] (8 x 16B per thread), prefetch A frags s=0
    {
        const _Float16* Ws = a.Wt + (size_t)a.wsel[0] * (DIM * DIM);
        f16x8 w[8];
        #pragma unroll
        for (int i = 0; i < 8; ++i)
            w[i] = *(const f16x8*)((const char*)Ws + i * 4096 + tid * 16);
        #pragma unroll
        for (int i = 0; i < 8; ++i) {
            const int p = i * 4096 + tid * 16;
            const int q = p ^ (((p >> 8) & 7) << 4);
            *(f16x8*)((char*)Wlds + q) = w[i];
        }
    }
    f16x8 af[2][4];
    #pragma unroll
    for (int ks = 0; ks < 4; ++ks)
        af[0][ks] = *(const f16x8*)(a.Aslot[0] + (size_t)r * DIM + ks * 32 + lg * 8);
    __syncthreads();

    #pragma unroll
    for (int s = 0; s < NSUB; ++s) {
        const int cur = s & 1, nxt = cur ^ 1;
        f16x8 w[8];
        if (s + 1 < NSUB) {
            const _Float16* Wn = a.Wt + (size_t)a.wsel[s + 1] * (DIM * DIM);
            #pragma unroll
            for (int i = 0; i < 8; ++i)
                w[i] = *(const f16x8*)((const char*)Wn + i * 4096 + tid * 16);
            const _Float16* An = a.Aslot[s + 1];
            #pragma unroll
            for (int ks = 0; ks < 4; ++ks)
                af[nxt][ks] = *(const f16x8*)(An + (size_t)r * DIM + ks * 32 + lg * 8);
        }
        #pragma unroll
        for (int ks = 0; ks < 4; ++ks) {
            const int cb = (ks * 32 + lg * 8) * 2;
            #pragma unroll
            for (int ct = 0; ct < 8; ++ct) {
                const int addr = (ct * 16 + lr) * 256 + (cb ^ sw);
                const f16x8 bf = *(const f16x8*)((const char*)Wlds + addr);
                acc[ct] = __builtin_amdgcn_mfma_f32_16x16x32_f16(af[cur][ks], bf, acc[ct], 0, 0, 0);
            }
        }
        __syncthreads();
        if (s + 1 < NSUB) {
            #pragma unroll
            for (int i = 0; i < 8; ++i) {
                const int p = i * 4096 + tid * 16;
                const int q = p ^ (((p >> 8) & 7) << 4);
                *(f16x8*)((char*)Wlds + q) = w[i];
            }
            __syncthreads();
        }
    }

    float bv[8];
    #pragma unroll
    for (int ct = 0; ct < 8; ++ct) bv[ct] = a.bias[ct * 16 + lr];

    // C/D layout: col = lane&15, row = (lane>>4)*4 + reg
    #pragma unroll
    for (int rg = 0; rg < 4; ++rg) {
        const int row = rowBase + lg * 4 + rg;
        const int rr = (row < a.N) ? row : a.N - 1;
        float v[8];
        float ss = 0.f;
        #pragma unroll
        for (int ct = 0; ct < 8; ++ct) {
            const float xval = (float)a.xin[(size_t)rr * DIM + ct * 16 + lr];
            const float tv = fmaxf(acc[ct][rg] + bv[ct], 0.f) + xval;
            v[ct] = tv;
            ss += tv * tv;
        }
        ss += __shfl_xor(ss, 1, 64);
        ss += __shfl_xor(ss, 2, 64);
        ss += __shfl_xor(ss, 4, 64);
        ss += __shfl_xor(ss, 8, 64);
        const float inv = 1.f / fmaxf(sqrtf(ss), 1e-12f);
        if (row < a.N) {
            #pragma unroll
            for (int ct = 0; ct < 8; ++ct) {
                const int col = ct * 16 + lr;
                const float ov = v[ct] * inv;
                if (a.outf) a.outf[(size_t)row * DIM + col] = ov;
                if (a.outh) a.outh[(size_t)row * DIM + col] = (_Float16)ov;
            }
        }
    }
}

// ---------------- launch ----------------

static inline size_t align_up(size_t v, size_t a) { return (v + a - 1) & ~(a - 1); }

extern "C" void kernel_launch(void* const* d_in, const int* in_sizes, int n_in,
                              void* d_out, int out_size, void* d_ws, size_t ws_size,
                              hipStream_t stream) {
    const float* x        = (const float*)d_in[0];
    const int* edge_index = (const int*)d_in[1];
    const int* edge_hop   = (const int*)d_in[2];
    const int* edge_type  = (const int*)d_in[3];
    const float* W_edge   = (const float*)d_in[4];
    const float* b_edge   = (const float*)d_in[5];
    const float* W_hop    = (const float*)d_in[6];
    const float* b_hop    = (const float*)d_in[7];
    float* out = (float*)d_out;

    int N = in_sizes[0] / DIM;   // 50000
    int E = in_sizes[2];         // 600000
    const int* srcA = edge_index;
    const int* dstA = edge_index + E;

    const int B1 = (E + CHUNK - 1) / CHUNK;     // 147
    const int NBKT = (N + 255) >> 8;            // 196
    const int n2 = NBKT * B1;                   // 28812

    size_t NSh = (size_t)N * DIM * sizeof(_Float16);
    size_t off = 0;
    char* wsb = (char*)d_ws;
    _Float16* xh0     = (_Float16*)(wsb + off);  off = align_up(off + NSh, 64);
    _Float16* xh1     = (_Float16*)(wsb + off);  off = align_up(off + NSh, 64);
    _Float16* xh2     = (_Float16*)(wsb + off);  off = align_up(off + NSh, 64);
    _Float16* xh3     = (_Float16*)(wsb + off);  off = align_up(off + NSh, 64);
    _Float16* Atype   = (_Float16*)(wsb + off);  off = align_up(off + 3 * NSh, 64);
    _Float16* Ahop    = (_Float16*)(wsb + off);  off = align_up(off + 7 * NSh, 64);
    _Float16* Wt      = (_Float16*)(wsb + off);  off = align_up(off + 13 * DIM * DIM * sizeof(_Float16), 64);
    int* ghist        = (int*)(wsb + off);       off = align_up(off + (size_t)n2 * 4, 64);
    int* partial      = (int*)(wsb + off);       off = align_up(off + (size_t)n2 * 4, 64);
    int* blockSums    = (int*)(wsb + off);       off = align_up(off + 64 * 4, 64);
    int* gcur         = (int*)(wsb + off);       off = align_up(off + (size_t)(n2 + 1) * 4, 64);
    int* row_ptr      = (int*)(wsb + off);       off = align_up(off + (size_t)(N + 1) * 4, 64);
    unsigned long long* ebuf = (unsigned long long*)(wsb + off);
                                                 off = align_up(off + (size_t)E * 8, 64);
    unsigned* csr     = (unsigned*)(wsb + off);  off = align_up(off + (size_t)E * 4, 64);
    float* bias_sums  = (float*)(wsb + off);     off = align_up(off + 4 * DIM * 4, 64);
    (void)ws_size;  // ~195 MB

    // CSR build (bucketed two-pass, hierarchical scan)
    k_hist1<<<B1, 256, 0, stream>>>(dstA, E, B1, NBKT, ghist);
    int nb2 = (n2 + 1023) / 1024;   // 29
    k_scan1<<<nb2, 1024, 0, stream>>>(ghist, n2, partial, blockSums);
    k_scan2<<<1, 64, 0, stream>>>(blockSums, nb2);
    k_scan3b<<<nb2, 1024, 0, stream>>>(partial, ghist, blockSums, n2, gcur);
    k_scat1<<<B1, 256, 0, stream>>>(srcA, dstA, edge_type, edge_hop, E, B1, NBKT, gcur, ebuf);
    k_finalize<<<NBKT, 256, 0, stream>>>(ebuf, gcur, E, B1, NBKT, N, csr, row_ptr);

    // merged conversions + bias
    const int NXB = (N * DIM / 8 + 255) / 256;   // 3125
    k_misc<<<NXB + 13 + 4, 256, 0, stream>>>(x, xh0, NXB, N * DIM,
                                             W_edge, W_hop, Wt, b_edge, b_hop, bias_sums);

    _Float16* xh_ptr[4] = { xh0, xh1, xh2, xh3 };
    const size_t NS = (size_t)N * DIM;

    for (int t = 0; t < NLAYER; ++t) {
        GatherArgs g;
        g.xt = xh_ptr[t];
        g.Atype = Atype; g.Ahop = Ahop;
        g.row_ptr = row_ptr; g.csr = csr; g.N = N;
        const int gbg = (N + 3) / 4;
        switch (t) {
            case 0: k_gather<0><<<gbg, 256, 0, stream>>>(g); break;
            case 1: k_gather<1><<<gbg, 256, 0, stream>>>(g); break;
            case 2: k_gather<2><<<gbg, 256, 0, stream>>>(g); break;
            default: k_gather<3><<<gbg, 256, 0, stream>>>(g); break;
        }

        GemmArgs m;
        m.Wt = Wt; m.xin = xh_ptr[t];
        m.bias = bias_sums + t * DIM;
        m.outf = (t == 3) ? out : nullptr;
        m.outh = (t < 3) ? xh_ptr[t + 1] : nullptr;
        m.N = N;
        const int nsub = t + 4;
        const int base = t * (t + 1) / 2;
        for (int s = 0; s < 3; ++s) { m.wsel[s] = s; m.Aslot[s] = Atype + (size_t)s * NS; }
        for (int j = 0; j <= t; ++j) {
            m.wsel[3 + j] = 3 + base + j;
            m.Aslot[3 + j] = Ahop + (size_t)PHYS[base + j] * NS;
        }
        for (int s = nsub; s < 7; ++s) { m.wsel[s] = 0; m.Aslot[s] = Atype; }

        const int gb = (N + 63) / 64;
        switch (nsub) {
            case 4: k_gemm<4><<<gb, 256, 0, stream>>>(m); break;
            case 5: k_gemm<5><<<gb, 256, 0, stream>>>(m); break;
            case 6: k_gemm<6><<<gb, 256, 0, stream>>>(m); break;
            default: k_gemm<7><<<gb, 256, 0, stream>>>(m); break;
        }
    }
}